// Round 10
// baseline (166.335 us; speedup 1.0000x reference)
//
#include <hip/hip_runtime.h>
#include <stdint.h>

typedef unsigned short u16;
typedef __attribute__((ext_vector_type(8))) short short8;   // 8 x bf16 (4 VGPRs)
typedef __attribute__((ext_vector_type(4))) short short4v;  // 4 x bf16
typedef __attribute__((ext_vector_type(4))) float f32x4;

#define AS1 __attribute__((address_space(1)))
#define AS3 __attribute__((address_space(3)))

__device__ __forceinline__ u16 f2bf(float f) {
  uint32_t x = __builtin_bit_cast(uint32_t, f);
  uint32_t r = (x + 0x7fffu + ((x >> 16) & 1u)) >> 16;   // RNE
  return (u16)r;
}
__device__ __forceinline__ float bf2f(u16 u) {
  return __builtin_bit_cast(float, (uint32_t)u << 16);
}

// ---------------- pack: fp32 -> bf16 conversions + weight concat ----------------
__device__ __forceinline__ void conv8(const float* __restrict__ s, u16* __restrict__ d, float sc) {
  float4 a = *(const float4*)s;
  float4 b = *(const float4*)(s + 4);
  union { u16 u[8]; uint4 v; } pk;
  pk.u[0] = f2bf(a.x * sc); pk.u[1] = f2bf(a.y * sc); pk.u[2] = f2bf(a.z * sc); pk.u[3] = f2bf(a.w * sc);
  pk.u[4] = f2bf(b.x * sc); pk.u[5] = f2bf(b.y * sc); pk.u[6] = f2bf(b.z * sc); pk.u[7] = f2bf(b.w * sc);
  *(uint4*)d = pk.v;
}
__device__ __forceinline__ void copy8f(const float* __restrict__ s, float* __restrict__ d, float sc) {
  float4 a = *(const float4*)s;
  float4 b = *(const float4*)(s + 4);
  a.x *= sc; a.y *= sc; a.z *= sc; a.w *= sc;
  b.x *= sc; b.y *= sc; b.z *= sc; b.w *= sc;
  *(float4*)d = a; *(float4*)(d + 4) = b;
}

__global__ void pack_kernel(const float* __restrict__ X,
                            const float* __restrict__ Wq, const float* __restrict__ bq,
                            const float* __restrict__ Wk, const float* __restrict__ bk,
                            const float* __restrict__ Wv, const float* __restrict__ bv,
                            const float* __restrict__ Wo,
                            u16* __restrict__ Xbf, u16* __restrict__ Wcat,
                            u16* __restrict__ Wobf, float* __restrict__ bcat) {
  int t = blockIdx.x * blockDim.x + threadIdx.x;
  if (t < 524288) { conv8(X + (size_t)t * 8, Xbf + (size_t)t * 8, 1.f); return; }
  t -= 524288;
  if (t < 131072) { conv8(Wq + (size_t)t * 8, Wcat + (size_t)t * 8, 0.125f); return; }   // fold D^-0.5
  t -= 131072;
  if (t < 131072) { conv8(Wk + (size_t)t * 8, Wcat + 1048576 + (size_t)t * 8, 1.f); return; }
  t -= 131072;
  if (t < 131072) { conv8(Wv + (size_t)t * 8, Wcat + 2097152 + (size_t)t * 8, 1.f); return; }
  t -= 131072;
  if (t < 131072) { conv8(Wo + (size_t)t * 8, Wobf + (size_t)t * 8, 1.f); return; }
  t -= 131072;
  if (t < 128) { copy8f(bq + t * 8, bcat + t * 8, 0.125f); return; }
  t -= 128;
  if (t < 128) { copy8f(bk + t * 8, bcat + 1024 + t * 8, 1.f); return; }
  t -= 128;
  if (t < 128) { copy8f(bv + t * 8, bcat + 2048 + t * 8, 1.f); return; }
}

// ---------------- bf16 GEMM, BK=32, XOR-swizzled LDS, 2-phase prefetch, 8 waves ----------
// Round-10: LDS-BW diagnosis. Per-CU LDS reads per K-step = waves x (MI+NI) KB at
// ~85 B/cy (m134) -> this, not latency or HBM, is gemm1's wall (R9: 144 KB/step ~ 2100 cy
// ~ measured iter time; MFMA only ~900 cy of it). Fix = fatter wave tiles: reads scale
// (MI+NI), work scales MI*NI. gemm1 now BM=128 x BN=384, 8 waves (2Mx4N) of 64x96
// (MI=4, NI=6: 10 KB reads per 24 MFMA; total LDS traffic 1.18 GB -> 655 MB), grid
// 32x8 = 256 = exactly 1 block/CU, LDS 64 KiB. Same 2-phase ledger: one barrier per
// K-step; stage(cur^1) issued after barrier, drained by the NEXT barrier's vmcnt(0) -
// in flight a full ~1200 cy iteration >= worst-case HBM latency.
// Swizzle unchanged (64B rows of 32 elems; all row offsets are multiples of 8 rows so
// (row>>1)&3 reduces to (lrow>>1)&3 on the read side).
template <int BN, int NWN, bool OUT_BF16>
__global__ __launch_bounds__(512, 2)
void gemm_bt(const u16* __restrict__ A, const u16* __restrict__ Bt,
             const float* __restrict__ bias, u16* __restrict__ Cbf,
             float* __restrict__ Cf, int M, int N, int K) {
  constexpr int SEG_A = 8;            // 128 rows / 16 rows-per-1KiB-segment
  constexpr int SEG_B = BN / 16;
  constexpr int NSEG = SEG_A + SEG_B; // 32 (BN=384) or 12 (BN=64)
  constexpr int LPW = (NSEG + 7) / 8; // global_load_lds per wave per stage
  constexpr int NWM = 8 / NWN;        // waves along M
  constexpr int MI = (128 / NWM) / 16;// M-frags per wave
  constexpr int NI = (BN / NWN) / 16; // N-frags per wave
  __shared__ u16 As[2][128 * 32];
  __shared__ u16 Bs[2][BN * 32];
  const int wv = threadIdx.x >> 6;    // 0..7
  const int lane = threadIdx.x & 63;
  const int bm = blockIdx.x, bn = blockIdx.y;
  const int wm = wv / NWN, wn = wv % NWN;
  const int lrow = lane & 15, quad = lane >> 4;

  f32x4 acc[MI][NI];
#pragma unroll
  for (int i = 0; i < MI; ++i)
#pragma unroll
    for (int j = 0; j < NI; ++j) acc[i][j] = (f32x4){0.f, 0.f, 0.f, 0.f};

  const long arow = (long)bm * 128;
  const long brow = (long)bn * BN;
  // staging: segment s covers rows s*16..s*16+15; lane -> row srow = lane>>2,
  // LDS slot = lane&3; source col-block = (lane&3)^((lane>>3)&3)
  const int srow = lane >> 2;
  const int scol = ((lane & 3) ^ ((lane >> 3) & 3)) * 8;   // element offset in row
  const int swz = (quad ^ ((lrow >> 1) & 3)) * 8;          // frag-read slot offset (elements)

  auto stage = [&](int nb, int k0) {
#pragma unroll
    for (int it = 0; it < LPW; ++it) {
      const int s = wv + it * 8;                // wave-uniform segment id
      if (s < NSEG) {                           // wave-uniform guard
        const u16* g;
        u16* l;
        if (s < SEG_A) {
          g = A + (arow + s * 16 + srow) * K + k0 + scol;
          l = (u16*)As[nb] + s * 512;           // wave-uniform LDS base; HW adds lane*16B
        } else {
          g = Bt + (brow + (s - SEG_A) * 16 + srow) * K + k0 + scol;
          l = (u16*)Bs[nb] + (s - SEG_A) * 512;
        }
        __builtin_amdgcn_global_load_lds((AS1 void*)g, (AS3 void*)l, 16, 0, 0);
      }
    }
  };

  stage(0, 0);                                  // prologue: tile 0 into buffer 0
  int cur = 0;
  for (int k0 = 0; k0 < K; k0 += 32) {
    // barrier drains this wave's outstanding global_load_lds (vmcnt) -> buf[cur] ready,
    // and guarantees every wave finished its ds_reads of buf[cur^1] last iteration.
    __syncthreads();
    if (k0 + 32 < K) stage(cur ^ 1, k0 + 32);   // prefetch next tile; drains NEXT iter

    short8 af[MI], bfr[NI];
#pragma unroll
    for (int mi = 0; mi < MI; ++mi)
      af[mi] = *(const short8*)(As[cur] + (wm * (MI * 16) + mi * 16 + lrow) * 32 + swz);
#pragma unroll
    for (int ni = 0; ni < NI; ++ni)
      bfr[ni] = *(const short8*)(Bs[cur] + (wn * (NI * 16) + ni * 16 + lrow) * 32 + swz);
#pragma unroll
    for (int mi = 0; mi < MI; ++mi)
#pragma unroll
      for (int ni = 0; ni < NI; ++ni)
        acc[mi][ni] = __builtin_amdgcn_mfma_f32_16x16x32_bf16(af[mi], bfr[ni], acc[mi][ni], 0, 0, 0);
    cur ^= 1;
  }

  // epilogue: C/D layout col=lane&15, row=quad*4+r (verified m89/m91)
#pragma unroll
  for (int mi = 0; mi < MI; ++mi) {
#pragma unroll
    for (int ni = 0; ni < NI; ++ni) {
      const int col = bn * BN + wn * (NI * 16) + ni * 16 + lrow;
      const float bv = bias[col];
#pragma unroll
      for (int r = 0; r < 4; ++r) {
        const int row = bm * 128 + wm * (MI * 16) + mi * 16 + quad * 4 + r;
        const float v = acc[mi][ni][r] + bv;
        if constexpr (OUT_BF16) Cbf[(long)row * N + col] = f2bf(v);
        else Cf[(long)row * N + col] = v;
      }
    }
  }
}

// ---------------- MFMA windowed attention: one wave per (b,h,chunk) ----------------
// (unchanged from round 7 — best measured)
#define NCH 205  // ceil(2048/10)
#define VR_STRIDE 68   // u16; 136B rows: 8B-aligned b64 writes, 2-way PV read conflicts
#define PB_STRIDE 72   // u16; 144B rows: 16B aligned (b128 reads)
#define WAVE_LDS (36 * VR_STRIDE + 16 * PB_STRIDE)   // 2448 + 1152 = 3600 u16 = 7200 B

__global__ __launch_bounds__(256)
void attn_kernel(const u16* __restrict__ QKV, u16* __restrict__ ctx) {
  __shared__ __align__(16) u16 lds[4 * WAVE_LDS];
  const int wv = threadIdx.x >> 6;
  const int lane = threadIdx.x & 63;
  u16* Vr = lds + wv * WAVE_LDS;      // [36 j][68] bf16 row-major V (rows >= L unstaged)
  u16* Pb = Vr + 36 * VR_STRIDE;      // [16 q][72] bf16 (P in row-major for A-frag)

  const int n = lane & 15, quad = lane >> 4;

  const int gw = blockIdx.x * 4 + wv;           // 6560 waves exactly
  const int b = gw / (16 * NCH);
  int rem = gw - b * 16 * NCH;
  const int h = rem / NCH;
  const int c = rem - h * NCH;
  const int cs = c * 10;
  const int nq = min(10, 2048 - cs);
  const int w0 = max(cs - 25, 0);
  const int L = cs + nq - w0;                   // window length, 10 <= L <= 35

  const long base = ((long)b * 2048) * 3072 + (long)h * 64;

  // zero Pb only (cols 48..71 must stay exact 0 for the k>=48 MFMA half)
  for (int idx = lane; idx < (16 * PB_STRIDE) / 8; idx += 64)
    *(uint4*)(Pb + idx * 8) = (uint4){0, 0, 0, 0};

  // stage V row-major: Vr[j][d] = V[w0+j][d]; 16B loads, 2x 8B LDS writes
#pragma unroll
  for (int it = 0; it < 5; ++it) {
    const int slot = it * 64 + lane;
    const int j = slot >> 3, c8 = slot & 7;
    if (j < L) {
      const uint4 v = *(const uint4*)(QKV + base + (long)(w0 + j) * 3072 + 2048 + c8 * 8);
      u16* wp = Vr + j * VR_STRIDE + c8 * 8;
      *(uint2*)wp = (uint2){v.x, v.y};
      *(uint2*)(wp + 4) = (uint2){v.z, v.w};
    }
  }

  // ---- scores = Q * K^T via MFMA (M=16 pad, N=48 = 3 tiles, K=64) ----
  const int mclamp = min(n, nq - 1);
  const long qrow = base + (long)(cs + mclamp) * 3072;
  short8 aq0 = *(const short8*)(QKV + qrow + quad * 8);
  short8 aq1 = *(const short8*)(QKV + qrow + 32 + quad * 8);

  f32x4 sc[3];
#pragma unroll
  for (int t = 0; t < 3; ++t) {
    const int jj = min(16 * t + n, L - 1);      // clamp: garbage masked later
    const long krow = base + (long)(w0 + jj) * 3072 + 1024;
    short8 bk0 = *(const short8*)(QKV + krow + quad * 8);
    short8 bk1 = *(const short8*)(QKV + krow + 32 + quad * 8);
    f32x4 z = (f32x4){0.f, 0.f, 0.f, 0.f};
    z = __builtin_amdgcn_mfma_f32_16x16x32_bf16(aq0, bk0, z, 0, 0, 0);
    sc[t] = __builtin_amdgcn_mfma_f32_16x16x32_bf16(aq1, bk1, z, 0, 0, 0);
  }

  // ---- softmax in C-layout (col = 16t+n, row = quad*4+r), write P to LDS bf16 ----
#pragma unroll
  for (int r = 0; r < 4; ++r) {
    const int i = cs + quad * 4 + r;
    const int jlo = max(i - 25, 0) - w0;
    float v0 = (n >= jlo && n < L)      ? sc[0][r] : -1e30f;
    float v1 = (16 + n >= jlo && 16 + n < L) ? sc[1][r] : -1e30f;
    float v2 = (32 + n >= jlo && 32 + n < L) ? sc[2][r] : -1e30f;
    float m = fmaxf(v0, fmaxf(v1, v2));
#pragma unroll
    for (int off = 8; off > 0; off >>= 1) m = fmaxf(m, __shfl_xor(m, off));  // 16-lane row groups
    float p0 = __expf(v0 - m), p1 = __expf(v1 - m), p2 = __expf(v2 - m);
    float sum = p0 + p1 + p2;
#pragma unroll
    for (int off = 8; off > 0; off >>= 1) sum += __shfl_xor(sum, off);
    const float inv = 1.f / sum;
    u16* prow = Pb + (quad * 4 + r) * PB_STRIDE;
    prow[n]      = f2bf(p0 * inv);
    prow[16 + n] = f2bf(p1 * inv);
    prow[32 + n] = f2bf(p2 * inv);
  }
  // same-wave LDS RAW: DS pipe in-order per wave; compiler inserts lgkmcnt waits

  // ---- O = P * V via MFMA (M=16, N=64 = 4 tiles, K=64) ----
  short8 ap0 = *(const short8*)(Pb + n * PB_STRIDE + quad * 8);
  short8 ap1 = *(const short8*)(Pb + n * PB_STRIDE + 32 + quad * 8);
  const int icap = (L - 1) * VR_STRIDE;
  const int ib0 = (quad * 8) * VR_STRIDE;
  const int ib1 = ib0 + 32 * VR_STRIDE;
  f32x4 o[4];
#pragma unroll
  for (int dt = 0; dt < 4; ++dt) {
    const u16* colp = Vr + dt * 16 + n;
    short8 bv0, bv1;
#pragma unroll
    for (int e = 0; e < 8; ++e) {
      int i0 = ib0 + e * VR_STRIDE; i0 = i0 < icap ? i0 : icap;
      int i1 = ib1 + e * VR_STRIDE; i1 = i1 < icap ? i1 : icap;
      bv0[e] = (short)colp[i0];
      bv1[e] = (short)colp[i1];
    }
    f32x4 z = (f32x4){0.f, 0.f, 0.f, 0.f};
    z = __builtin_amdgcn_mfma_f32_16x16x32_bf16(ap0, bv0, z, 0, 0, 0);
    o[dt] = __builtin_amdgcn_mfma_f32_16x16x32_bf16(ap1, bv1, z, 0, 0, 0);
  }

  // ---- store (C-layout: col = d within tile, row = quad*4+r) ----
#pragma unroll
  for (int dt = 0; dt < 4; ++dt) {
#pragma unroll
    for (int r = 0; r < 4; ++r) {
      const int row = quad * 4 + r;
      if (row < nq)
        ctx[((long)b * 2048 + cs + row) * 1024 + h * 64 + dt * 16 + n] = f2bf(o[dt][r]);
    }
  }
}

extern "C" void kernel_launch(void* const* d_in, const int* in_sizes, int n_in,
                              void* d_out, int out_size, void* d_ws, size_t ws_size,
                              hipStream_t stream) {
  const float* X  = (const float*)d_in[0];
  const float* Wq = (const float*)d_in[1];
  const float* bq = (const float*)d_in[2];
  const float* Wk = (const float*)d_in[3];
  const float* bk = (const float*)d_in[4];
  const float* Wv = (const float*)d_in[5];
  const float* bv = (const float*)d_in[6];
  const float* Wo = (const float*)d_in[7];
  const float* bo = (const float*)d_in[8];
  float* out = (float*)d_out;

  char* ws = (char*)d_ws;
  u16* Xbf   = (u16*)(ws);                  // [4096,1024] bf16   8,388,608 B
  u16* Wcat  = (u16*)(ws + 8388608);        // [3072,1024] bf16   6,291,456 B
  u16* Wobf  = (u16*)(ws + 14680064);       // [1024,1024] bf16   2,097,152 B
  float* bcat = (float*)(ws + 16777216);    // [3072] f32            12,288 B
  u16* QKV   = (u16*)(ws + 16789504);       // [4096,3072] bf16  25,165,824 B
  u16* ctx   = (u16*)(ws + 41955328);       // [4096,1024] bf16   8,388,608 B

  pack_kernel<<<4098, 256, 0, stream>>>(X, Wq, bq, Wk, bk, Wv, bv, Wo, Xbf, Wcat, Wobf, bcat);
  gemm_bt<384, 4, true ><<<dim3(32, 8), 512, 0, stream>>>(Xbf, Wcat, bcat, QKV, nullptr, 4096, 3072, 1024);
  attn_kernel<<<1640, 256, 0, stream>>>(QKV, ctx);
  gemm_bt<64, 2, false><<<dim3(32, 16), 512, 0, stream>>>(ctx, Wobf, bo, nullptr, out, 4096, 1024, 1024);
}

// Round 12
// 152.056 us; speedup vs baseline: 1.0939x; 1.0939x over previous
//
#include <hip/hip_runtime.h>
#include <stdint.h>

typedef unsigned short u16;
typedef __attribute__((ext_vector_type(8))) short short8;   // 8 x bf16 (4 VGPRs)
typedef __attribute__((ext_vector_type(4))) short short4v;  // 4 x bf16
typedef __attribute__((ext_vector_type(4))) float f32x4;

#define AS1 __attribute__((address_space(1)))
#define AS3 __attribute__((address_space(3)))

__device__ __forceinline__ u16 f2bf(float f) {
  uint32_t x = __builtin_bit_cast(uint32_t, f);
  uint32_t r = (x + 0x7fffu + ((x >> 16) & 1u)) >> 16;   // RNE
  return (u16)r;
}
__device__ __forceinline__ float bf2f(u16 u) {
  return __builtin_bit_cast(float, (uint32_t)u << 16);
}

// ---------------- pack: fp32 -> bf16 conversions + weight concat ----------------
__device__ __forceinline__ void conv8(const float* __restrict__ s, u16* __restrict__ d, float sc) {
  float4 a = *(const float4*)s;
  float4 b = *(const float4*)(s + 4);
  union { u16 u[8]; uint4 v; } pk;
  pk.u[0] = f2bf(a.x * sc); pk.u[1] = f2bf(a.y * sc); pk.u[2] = f2bf(a.z * sc); pk.u[3] = f2bf(a.w * sc);
  pk.u[4] = f2bf(b.x * sc); pk.u[5] = f2bf(b.y * sc); pk.u[6] = f2bf(b.z * sc); pk.u[7] = f2bf(b.w * sc);
  *(uint4*)d = pk.v;
}
__device__ __forceinline__ void copy8f(const float* __restrict__ s, float* __restrict__ d, float sc) {
  float4 a = *(const float4*)s;
  float4 b = *(const float4*)(s + 4);
  a.x *= sc; a.y *= sc; a.z *= sc; a.w *= sc;
  b.x *= sc; b.y *= sc; b.z *= sc; b.w *= sc;
  *(float4*)d = a; *(float4*)(d + 4) = b;
}

__global__ void pack_kernel(const float* __restrict__ X,
                            const float* __restrict__ Wq, const float* __restrict__ bq,
                            const float* __restrict__ Wk, const float* __restrict__ bk,
                            const float* __restrict__ Wv, const float* __restrict__ bv,
                            const float* __restrict__ Wo,
                            u16* __restrict__ Xbf, u16* __restrict__ Wcat,
                            u16* __restrict__ Wobf, float* __restrict__ bcat) {
  int t = blockIdx.x * blockDim.x + threadIdx.x;
  if (t < 524288) { conv8(X + (size_t)t * 8, Xbf + (size_t)t * 8, 1.f); return; }
  t -= 524288;
  if (t < 131072) { conv8(Wq + (size_t)t * 8, Wcat + (size_t)t * 8, 0.125f); return; }   // fold D^-0.5
  t -= 131072;
  if (t < 131072) { conv8(Wk + (size_t)t * 8, Wcat + 1048576 + (size_t)t * 8, 1.f); return; }
  t -= 131072;
  if (t < 131072) { conv8(Wv + (size_t)t * 8, Wcat + 2097152 + (size_t)t * 8, 1.f); return; }
  t -= 131072;
  if (t < 131072) { conv8(Wo + (size_t)t * 8, Wobf + (size_t)t * 8, 1.f); return; }
  t -= 131072;
  if (t < 128) { copy8f(bq + t * 8, bcat + t * 8, 0.125f); return; }
  t -= 128;
  if (t < 128) { copy8f(bk + t * 8, bcat + 1024 + t * 8, 1.f); return; }
  t -= 128;
  if (t < 128) { copy8f(bv + t * 8, bcat + 2048 + t * 8, 1.f); return; }
}

// ---------------- bf16 GEMM, BK=32, XOR-swizzled LDS, 2-phase prefetch, 8 waves ----------
// Best-measured config (round 6/9). Structural ledger for this shape (M=4096, K=1024):
// t_step ~ LDS_cycles + exposed_stage_latency / blocks_per_CU. >=3 blocks/CU configs all
// land 37-42 us; 1 block/CU configs 41-53 (R8 8-phase 256^2, R10 fat 384-tile). Also
// null: counted-vmcnt depth-2 (-8%), XCD swizzle (-2%). gemm1 plateau ~37 us.
template <int BN, bool OUT_BF16>
__global__ __launch_bounds__(512)
void gemm_bt(const u16* __restrict__ A, const u16* __restrict__ Bt,
             const float* __restrict__ bias, u16* __restrict__ Cbf,
             float* __restrict__ Cf, int M, int N, int K) {
  constexpr int SEG_A = 8;            // 128 rows / 16 rows-per-1KiB-segment
  constexpr int SEG_B = BN / 16;
  constexpr int NSEG = SEG_A + SEG_B; // 16 (BN=128) or 12 (BN=64)
  constexpr int NWN = BN / 32;        // waves along N (each covers 32 cols): 4 or 2
  constexpr int NWM = 8 / NWN;        // waves along M: 2 or 4
  constexpr int MI = 128 / (NWM * 16);// M-frags per wave: 4 or 2
  __shared__ u16 As[2][128 * 32];
  __shared__ u16 Bs[2][BN * 32];
  const int wv = threadIdx.x >> 6;    // 0..7
  const int lane = threadIdx.x & 63;
  const int bm = blockIdx.x, bn = blockIdx.y;
  const int wm = wv / NWN, wn = wv % NWN;
  const int lrow = lane & 15, quad = lane >> 4;

  f32x4 acc[MI][2];
#pragma unroll
  for (int i = 0; i < MI; ++i)
#pragma unroll
    for (int j = 0; j < 2; ++j) acc[i][j] = (f32x4){0.f, 0.f, 0.f, 0.f};

  const long arow = (long)bm * 128;
  const long brow = (long)bn * BN;
  // staging: segment s covers rows s*16..s*16+15; lane -> row srow = lane>>2,
  // LDS slot = lane&3; source col-block = (lane&3)^((lane>>3)&3)
  const int srow = lane >> 2;
  const int scol = ((lane & 3) ^ ((lane >> 3) & 3)) * 8;   // element offset in row
  const int swz = (quad ^ ((lrow >> 1) & 3)) * 8;          // frag-read slot offset (elements)

  auto stage = [&](int nb, int k0) {
#pragma unroll
    for (int it = 0; it < 2; ++it) {
      const int s = wv + it * 8;                // wave-uniform segment id
      if (s < NSEG) {                           // wave-uniform guard (NSEG=12 case)
        const u16* g;
        u16* l;
        if (s < SEG_A) {
          g = A + (arow + s * 16 + srow) * K + k0 + scol;
          l = (u16*)As[nb] + s * 512;           // wave-uniform LDS base; HW adds lane*16B
        } else {
          g = Bt + (brow + (s - SEG_A) * 16 + srow) * K + k0 + scol;
          l = (u16*)Bs[nb] + (s - SEG_A) * 512;
        }
        __builtin_amdgcn_global_load_lds((AS1 void*)g, (AS3 void*)l, 16, 0, 0);
      }
    }
  };

  stage(0, 0);                                  // prologue: tile 0 into buffer 0
  int cur = 0;
  for (int k0 = 0; k0 < K; k0 += 32) {
    // barrier drains this wave's outstanding global_load_lds (vmcnt) -> buf[cur] ready,
    // and guarantees every wave finished its ds_reads of buf[cur^1] last iteration.
    __syncthreads();
    if (k0 + 32 < K) stage(cur ^ 1, k0 + 32);   // prefetch next tile; drains NEXT iter

    short8 af[MI], bfr[2];
#pragma unroll
    for (int mi = 0; mi < MI; ++mi)
      af[mi] = *(const short8*)(As[cur] + (wm * (MI * 16) + mi * 16 + lrow) * 32 + swz);
#pragma unroll
    for (int ni = 0; ni < 2; ++ni)
      bfr[ni] = *(const short8*)(Bs[cur] + (wn * 32 + ni * 16 + lrow) * 32 + swz);
#pragma unroll
    for (int mi = 0; mi < MI; ++mi)
#pragma unroll
      for (int ni = 0; ni < 2; ++ni)
        acc[mi][ni] = __builtin_amdgcn_mfma_f32_16x16x32_bf16(af[mi], bfr[ni], acc[mi][ni], 0, 0, 0);
    cur ^= 1;
  }

  // epilogue: C/D layout col=lane&15, row=quad*4+r (verified m89/m91)
#pragma unroll
  for (int mi = 0; mi < MI; ++mi) {
#pragma unroll
    for (int ni = 0; ni < 2; ++ni) {
      const int col = bn * BN + wn * 32 + ni * 16 + lrow;
      const float bv = bias[col];
#pragma unroll
      for (int r = 0; r < 4; ++r) {
        const int row = bm * 128 + wm * (MI * 16) + mi * 16 + quad * 4 + r;
        const float v = acc[mi][ni][r] + bv;
        if constexpr (OUT_BF16) Cbf[(long)row * N + col] = f2bf(v);
        else Cf[(long)row * N + col] = v;
      }
    }
  }
}

// ---------------- MFMA windowed attention: one wave per 16 consecutive queries ----------
// Wave = 16 queries (2048 = 128x16, no tail; all M-rows real) instead of one 10-row chunk
// (was 10/16 rows used, 3.3x K/V window overlap). Window for rows q0..q0+15:
// w0 = max(q0-25,0), end = chunk_end(q0+15), L = end-w0 <= 50 -> N=64 scores (4 tiles).
// Mask gains a per-row UPPER bound jhi = min(i/10*10+10, 2048) - w0. Masked P =
// expf(-huge) = exactly 0, so clamped (finite) V rows contribute exactly 0 ->
// value-identical. Waves 6560 -> 4096, HBM ~82 -> ~61 MB, decode pure shifts,
// Pb zero-init gone (all 64 P cols written). LDS 9104 B/wave -> 4 blocks/CU.
#define VR_STRIDE 68   // u16; 136B rows: 8B-aligned b64 writes, 2-way PV read conflicts
#define PB_STRIDE 72   // u16; 144B rows: 16B aligned (b128 reads)
#define WAVE_LDS (50 * VR_STRIDE + 16 * PB_STRIDE)   // 3400 + 1152 = 4552 u16 = 9104 B

__global__ __launch_bounds__(256)
void attn_kernel(const u16* __restrict__ QKV, u16* __restrict__ ctx) {
  __shared__ __align__(16) u16 lds[4 * WAVE_LDS];
  const int wv = threadIdx.x >> 6;
  const int lane = threadIdx.x & 63;
  u16* Vr = lds + wv * WAVE_LDS;      // [50 j][68] bf16 row-major V (rows >= L unstaged)
  u16* Pb = Vr + 50 * VR_STRIDE;      // [16 q][72] bf16 (P in row-major for A-frag)

  const int n = lane & 15, quad = lane >> 4;

  const int gw = blockIdx.x * 4 + wv;           // 4096 waves exactly
  const int b = gw >> 11;                       // 2048 waves per batch (16 h x 128 groups)
  const int rem = gw & 2047;
  const int h = rem >> 7;
  const int g = rem & 127;
  const int q0 = g * 16;
  const int w0 = max(q0 - 25, 0);
  const int end = min(((q0 + 15) / 10) * 10 + 10, 2048);   // chunk_end of last row
  const int L = end - w0;                       // window length, 20 <= L <= 50

  const long base = ((long)b * 2048) * 3072 + (long)h * 64;

  // stage V row-major: Vr[j][d] = V[w0+j][d]; 16B loads, 2x 8B LDS writes
  // slot = it*64+lane covers (j = slot>>3, c8 = slot&7); L rows x 8 slots <= 400 < 448
#pragma unroll
  for (int it = 0; it < 7; ++it) {
    const int slot = it * 64 + lane;
    const int j = slot >> 3, c8 = slot & 7;
    if (j < L) {
      const uint4 v = *(const uint4*)(QKV + base + (long)(w0 + j) * 3072 + 2048 + c8 * 8);
      u16* wp = Vr + j * VR_STRIDE + c8 * 8;
      *(uint2*)wp = (uint2){v.x, v.y};
      *(uint2*)(wp + 4) = (uint2){v.z, v.w};
    }
  }

  // ---- scores = Q * K^T via MFMA (M=16, N=64 = 4 tiles, K=64) ----
  // A-frag: lane holds Q[m=n][k=quad*8+idx+32*s]  (direct 16B global loads; row q0+n)
  const long qrow = base + (long)(q0 + n) * 3072;
  short8 aq0 = *(const short8*)(QKV + qrow + quad * 8);
  short8 aq1 = *(const short8*)(QKV + qrow + 32 + quad * 8);

  f32x4 sc[4];
#pragma unroll
  for (int t = 0; t < 4; ++t) {
    const int jj = min(16 * t + n, L - 1);      // clamp: garbage masked later
    const long krow = base + (long)(w0 + jj) * 3072 + 1024;
    short8 bk0 = *(const short8*)(QKV + krow + quad * 8);
    short8 bk1 = *(const short8*)(QKV + krow + 32 + quad * 8);
    f32x4 z = (f32x4){0.f, 0.f, 0.f, 0.f};
    z = __builtin_amdgcn_mfma_f32_16x16x32_bf16(aq0, bk0, z, 0, 0, 0);
    sc[t] = __builtin_amdgcn_mfma_f32_16x16x32_bf16(aq1, bk1, z, 0, 0, 0);
  }

  // ---- softmax in C-layout (col = 16t+n, row = quad*4+r), write P to LDS bf16 ----
#pragma unroll
  for (int r = 0; r < 4; ++r) {
    const int i = q0 + quad * 4 + r;            // query index (all 16 rows real)
    const int jlo = max(i - 25, 0) - w0;
    const int jhi = min((i / 10) * 10 + 10, 2048) - w0;    // per-row chunk end (<= L)
    float v0 = (n >= jlo && n < jhi)           ? sc[0][r] : -1e30f;
    float v1 = (16 + n >= jlo && 16 + n < jhi) ? sc[1][r] : -1e30f;
    float v2 = (32 + n >= jlo && 32 + n < jhi) ? sc[2][r] : -1e30f;
    float v3 = (48 + n >= jlo && 48 + n < jhi) ? sc[3][r] : -1e30f;
    float m = fmaxf(fmaxf(v0, v1), fmaxf(v2, v3));
#pragma unroll
    for (int off = 8; off > 0; off >>= 1) m = fmaxf(m, __shfl_xor(m, off));  // 16-lane row groups
    float p0 = __expf(v0 - m), p1 = __expf(v1 - m), p2 = __expf(v2 - m), p3 = __expf(v3 - m);
    float sum = (p0 + p1) + (p2 + p3);
#pragma unroll
    for (int off = 8; off > 0; off >>= 1) sum += __shfl_xor(sum, off);
    const float inv = 1.f / sum;
    u16* prow = Pb + (quad * 4 + r) * PB_STRIDE;
    prow[n]      = f2bf(p0 * inv);
    prow[16 + n] = f2bf(p1 * inv);
    prow[32 + n] = f2bf(p2 * inv);
    prow[48 + n] = f2bf(p3 * inv);
  }
  // same-wave LDS RAW: DS pipe in-order per wave; compiler inserts lgkmcnt waits

  // ---- O = P * V via MFMA (M=16, N=64 = 4 tiles, K=64) ----
  // B-frag columns from row-major Vr with clamped row index (P==0 for k>=jhi kills them)
  short8 ap0 = *(const short8*)(Pb + n * PB_STRIDE + quad * 8);        // k = quad*8+idx
  short8 ap1 = *(const short8*)(Pb + n * PB_STRIDE + 32 + quad * 8);   // k = 32+quad*8+idx
  const int icap = (L - 1) * VR_STRIDE;         // clamp cap in u16 units
  const int ib0 = (quad * 8) * VR_STRIDE;       // bv0 row base
  const int ib1 = ib0 + 32 * VR_STRIDE;         // bv1 row base
  f32x4 o[4];
#pragma unroll
  for (int dt = 0; dt < 4; ++dt) {
    const u16* colp = Vr + dt * 16 + n;         // column base: d = dt*16+n
    short8 bv0, bv1;
#pragma unroll
    for (int e = 0; e < 8; ++e) {
      int i0 = ib0 + e * VR_STRIDE; i0 = i0 < icap ? i0 : icap;
      int i1 = ib1 + e * VR_STRIDE; i1 = i1 < icap ? i1 : icap;
      bv0[e] = (short)colp[i0];
      bv1[e] = (short)colp[i1];
    }
    f32x4 z = (f32x4){0.f, 0.f, 0.f, 0.f};
    z = __builtin_amdgcn_mfma_f32_16x16x32_bf16(ap0, bv0, z, 0, 0, 0);
    o[dt] = __builtin_amdgcn_mfma_f32_16x16x32_bf16(ap1, bv1, z, 0, 0, 0);
  }

  // ---- store (C-layout: col = d within tile, row = quad*4+r; all rows valid) ----
#pragma unroll
  for (int dt = 0; dt < 4; ++dt) {
#pragma unroll
    for (int r = 0; r < 4; ++r) {
      const int row = quad * 4 + r;
      ctx[((long)b * 2048 + q0 + row) * 1024 + h * 64 + dt * 16 + n] = f2bf(o[dt][r]);
    }
  }
}

extern "C" void kernel_launch(void* const* d_in, const int* in_sizes, int n_in,
                              void* d_out, int out_size, void* d_ws, size_t ws_size,
                              hipStream_t stream) {
  const float* X  = (const float*)d_in[0];
  const float* Wq = (const float*)d_in[1];
  const float* bq = (const float*)d_in[2];
  const float* Wk = (const float*)d_in[3];
  const float* bk = (const float*)d_in[4];
  const float* Wv = (const float*)d_in[5];
  const float* bv = (const float*)d_in[6];
  const float* Wo = (const float*)d_in[7];
  const float* bo = (const float*)d_in[8];
  float* out = (float*)d_out;

  char* ws = (char*)d_ws;
  u16* Xbf   = (u16*)(ws);                  // [4096,1024] bf16   8,388,608 B
  u16* Wcat  = (u16*)(ws + 8388608);        // [3072,1024] bf16   6,291,456 B
  u16* Wobf  = (u16*)(ws + 14680064);       // [1024,1024] bf16   2,097,152 B
  float* bcat = (float*)(ws + 16777216);    // [3072] f32            12,288 B
  u16* QKV   = (u16*)(ws + 16789504);       // [4096,3072] bf16  25,165,824 B
  u16* ctx   = (u16*)(ws + 41955328);       // [4096,1024] bf16   8,388,608 B

  pack_kernel<<<4098, 256, 0, stream>>>(X, Wq, bq, Wk, bk, Wv, bv, Wo, Xbf, Wcat, Wobf, bcat);
  gemm_bt<128, true ><<<dim3(32, 24), 512, 0, stream>>>(Xbf, Wcat, bcat, QKV, nullptr, 4096, 3072, 1024);
  attn_kernel<<<1024, 256, 0, stream>>>(QKV, ctx);
  gemm_bt<64, false><<<dim3(32, 16), 512, 0, stream>>>(ctx, Wobf, bo, nullptr, out, 4096, 1024, 1024);
}